// Round 3
// baseline (154.947 us; speedup 1.0000x reference)
//
#include <hip/hip_runtime.h>
#include <hip/hip_bf16.h>
#include <math.h>

// Problem constants
#define P_TOTAL 18378
// param breakpoints (floats): w1 [0,400), b1 [400,416), w2 [416,13216),
// b2 [13216,13248), w3 [13248,18368), b3 [18368,18378)

typedef __attribute__((ext_vector_type(8))) short short8;
typedef __attribute__((ext_vector_type(4))) float float4v;
typedef __attribute__((ext_vector_type(16))) float float16;

__device__ __forceinline__ unsigned short f2bf(float f) {
    union { float f; unsigned u; } v; v.f = f;
    unsigned r = v.u + 0x7fffu + ((v.u >> 16) & 1u);
    return (unsigned short)(r >> 16);
}
__device__ __forceinline__ float bf2f(unsigned short h) {
    union { unsigned u; float f; } v; v.u = ((unsigned)h) << 16;
    return v.f;
}

// ---------------- Kernel 0: param prep ----------------
// blocks 0..63: conv2 weights -> bf16 [init][tap][co=32][cin=16]
// blocks 64..127: conv1 weights -> bf16 A-layout [init][m=co16][k=32pad]
__global__ __launch_bounds__(256) void prep_kernel(const float* __restrict__ params,
                                                   unsigned short* __restrict__ wswz,
                                                   unsigned short* __restrict__ Amat) {
    int blk = blockIdx.x;
    if (blk < 64) {
        int i = blk;
        const float* w2 = params + (size_t)i * P_TOTAL + 416;   // [co32][cin16][5][5]
        unsigned short* dst = wswz + (size_t)i * 12800;
        for (int k = threadIdx.x; k < 12800; k += 256) {
            int co = k / 400;
            int r = k - co * 400;
            int cin = r / 25;
            int s = r - cin * 25;   // s = ky*5+kx
            dst[(s * 32 + co) * 16 + cin] = f2bf(w2[k]);
        }
    } else {
        int i = blk - 64;
        const float* w1 = params + (size_t)i * P_TOTAL;          // [co16][25]
        unsigned short* dst = Amat + (size_t)i * 512;
        for (int e = threadIdx.x; e < 512; e += 256) {
            int m = e >> 5, k = e & 31;
            dst[e] = (k < 25) ? f2bf(w1[m * 25 + k]) : (unsigned short)0;
        }
    }
}

// ---------------- Kernel 1: im2col of batch (shared across all inits) ----------------
// Bmat[img][c][32k] bf16, c = pp*4+q, pp = py*12+px (pooled pixel), q = dy*2+dx.
// Bmat[img][c][k] = img[2py+dy+ky][2px+dx+kx], k = ky*5+kx (<25; zeros for 25..31).
__global__ __launch_bounds__(256) void im2col_kernel(const float* __restrict__ batch,
                                                     unsigned short* __restrict__ Bmat) {
    __shared__ float img[784];
    int j = blockIdx.x;
    int t = threadIdx.x;
    const float* ip = batch + j * 784;
    for (int k = t; k < 784; k += 256) img[k] = ip[k];
    __syncthreads();
    unsigned short* dst = Bmat + (size_t)j * 18432;
    for (int task = t; task < 2304; task += 256) {
        int c = task >> 2, kh = task & 3;
        int pp = c >> 2, q = c & 3;
        int py = pp / 12, px = pp - py * 12;
        int y0 = 2 * py + (q >> 1);
        int x0 = 2 * px + (q & 1);
        unsigned short ov[8] __attribute__((aligned(16)));
#pragma unroll
        for (int u = 0; u < 8; ++u) {
            int k = kh * 8 + u;
            float v = 0.f;
            if (k < 25) {
                int ky = k / 5, kx = k - ky * 5;
                v = img[(y0 + ky) * 28 + x0 + kx];
            }
            ov[u] = f2bf(v);
        }
        *(uint4*)(dst + c * 32 + kh * 8) = *(const uint4*)ov;
    }
}

// ---------------- Kernel 2: conv1 as one-shot K=32 MFMA GEMM + pool + ReLU ----------------
// Grid = 128 img x 4 init-groups = 512 blocks, 256 thr (4 waves).
// Wave w handles inits ig*16 + w*4 .. +3 (4 M-tiles of 16 co... M-tile = one init's 16 co).
// N = 576 conv pixels = 36 tiles of 16 (4 pooled pixels x 4 quad).
// One mfma_16x16x32 per (M-tile, N-tile); pooling via 2 quad shuffles.
#define B_ROW 40   // LDS row stride (elems) for Bmat: 80 B -> conflict-free b128
__global__ __launch_bounds__(256) void conv1_gemm_kernel(
        const float* __restrict__ params,
        const unsigned short* __restrict__ Amat,   // [64 init][16 m][32 k]
        const unsigned short* __restrict__ Bmat,   // [img][576 c][32 k]
        unsigned short* __restrict__ act1) {       // [pair][144 pix][16 cin]
    __shared__ unsigned short blds[576 * B_ROW];   // 46080 B
    __shared__ unsigned short alds[16 * 512];      // 16384 B
    __shared__ float b1s[256];                     // 1024 B  (total 63488 B)
    int blk = blockIdx.x;
    int j  = blk >> 2;       // image
    int ig = blk & 3;        // init group (16 inits)
    int t = threadIdx.x;

    { // stage A (16 KB straight copy)
        const uint4* src = (const uint4*)(Amat + (size_t)ig * 16 * 512);
        uint4* dst = (uint4*)alds;
        for (int k = t; k < 1024; k += 256) dst[k] = src[k];
    }
    { // stage B with padded rows
        const uint4* src = (const uint4*)(Bmat + (size_t)j * 18432);
        for (int k = t; k < 2304; k += 256) {
            int c = k >> 2, kh = k & 3;
            *(uint4*)(blds + c * B_ROW + kh * 8) = src[k];
        }
    }
    { // stage b1 biases for 16 inits
        int il = t >> 4, co = t & 15;
        b1s[t] = params[(size_t)(ig * 16 + il) * P_TOTAL + 400 + co];
    }
    __syncthreads();

    int w = t >> 6, lane = t & 63;
    int m = lane & 15;        // A row (co) / B col (pixel)
    int kh4 = lane >> 4;      // k-group: k = kh4*8 + j
    int q = lane & 3;         // pool quadrant (col % 4)
    int ppl = (lane >> 2) & 3;// pooled pixel within N-tile

    short8 afr[4];
    float bias[4][4];
#pragma unroll
    for (int mt = 0; mt < 4; ++mt) {
        int il = w * 4 + mt;
        afr[mt] = *(const short8*)(alds + il * 512 + m * 32 + kh4 * 8);
#pragma unroll
        for (int r = 0; r < 4; ++r) bias[mt][r] = b1s[il * 16 + kh4 * 4 + r];
    }

#pragma unroll 4
    for (int nt = 0; nt < 36; ++nt) {
        short8 bfr = *(const short8*)(blds + (nt * 16 + m) * B_ROW + kh4 * 8);
#pragma unroll
        for (int mt = 0; mt < 4; ++mt) {
            float4v acc = {0.f, 0.f, 0.f, 0.f};
            acc = __builtin_amdgcn_mfma_f32_16x16x32_bf16(afr[mt], bfr, acc, 0, 0, 0);
            // D layout: col(pixel)=lane&15, row(co)=kh4*4+r. Pool = max over q (cols 0..3 of quad).
            unsigned short ov[4];
#pragma unroll
            for (int r = 0; r < 4; ++r) {
                float v = acc[r];
                v = fmaxf(v, __shfl_xor(v, 1));
                v = fmaxf(v, __shfl_xor(v, 2));
                v = fmaxf(v + bias[mt][r], 0.f);
                ov[r] = f2bf(v);
            }
            if (q == 0) {
                int init = ig * 16 + w * 4 + mt;
                int pp = nt * 4 + ppl;
                uint2 pk;
                pk.x = (unsigned)ov[0] | ((unsigned)ov[1] << 16);
                pk.y = (unsigned)ov[2] | ((unsigned)ov[3] << 16);
                *(uint2*)(act1 + ((size_t)(init * 128 + j) * 144 + pp) * 16 + kh4 * 4) = pk;
            }
        }
    }
}

// ---------------- Kernel 3: conv2 via MFMA implicit GEMM ----------------
#define A1_PIX_STRIDE 24        // elems (48 B) in LDS
#define IMG_LDS (144 * 24)      // 3456 elems = 6912 B per image
__global__ __launch_bounds__(256) void conv2_mfma_kernel(
        const float* __restrict__ params,
        const unsigned short* __restrict__ act1,   // [pair][144][16] bf16
        const unsigned short* __restrict__ wswz,   // [init][25][32][16] bf16
        unsigned short* __restrict__ act2) {       // [pair][32co][16pp] bf16
    __shared__ char smem[58880];
    unsigned short* wlds = (unsigned short*)smem;            // 25600 B
    unsigned short* a1s  = (unsigned short*)(smem + 25600);  // 27648 B
    float* scratch       = (float*)(smem + 25600);           // 33280 B (reuses a1s)

    int b = blockIdx.x;
    int i = b >> 5;           // init
    int g = b & 31;           // image group
    int jbase = g * 4;
    int t = threadIdx.x;
    int w = t >> 6;           // wave = image index within group
    int lane = t & 63;

    {
        const uint4* src = (const uint4*)(wswz + (size_t)i * 12800);
        uint4* dst = (uint4*)wlds;
        for (int k = t; k < 1600; k += 256) dst[k] = src[k];
    }
    {
        for (int k = t; k < 1152; k += 256) {
            int img = k / 288;
            int rem = k - img * 288;
            int pix = rem >> 1;
            int h   = rem & 1;
            const uint4* src = (const uint4*)(act1 +
                ((size_t)(i * 128 + jbase + img) * 144 + pix) * 16 + h * 8);
            uint4* dst = (uint4*)(a1s + img * IMG_LDS + pix * A1_PIX_STRIDE + h * 8);
            *dst = *src;
        }
    }
    __syncthreads();

    int n = lane & 31;
    int h = lane >> 5;
    const short8* aptr = (const short8*)(wlds + n * 16 + h * 8);
    int y0 = n >> 3, x0 = n & 7;
    const unsigned short* bbase = a1s + w * IMG_LDS;
    const short8* bptr0 = (const short8*)(bbase + ((y0    ) * 12 + x0) * A1_PIX_STRIDE + h * 8);
    const short8* bptr1 = (const short8*)(bbase + ((y0 + 4) * 12 + x0) * A1_PIX_STRIDE + h * 8);

    float16 acc0 = {};
    float16 acc1 = {};
#pragma unroll
    for (int ky = 0; ky < 5; ++ky) {
#pragma unroll
        for (int kx = 0; kx < 5; ++kx) {
            int tap = ky * 5 + kx;
            short8 af = aptr[tap * 64];
            int bo = (ky * 12 + kx) * 3;
            short8 b0 = bptr0[bo];
            short8 b1 = bptr1[bo];
            acc0 = __builtin_amdgcn_mfma_f32_32x32x16_bf16(af, b0, acc0, 0, 0, 0);
            acc1 = __builtin_amdgcn_mfma_f32_32x32x16_bf16(af, b1, acc1, 0, 0, 0);
        }
    }
    __syncthreads();

    float* sw = scratch + w * 2080;
#pragma unroll
    for (int r = 0; r < 16; ++r) {
        int co = (r & 3) + 8 * (r >> 2) + 4 * h;
        sw[co * 65 + n]      = acc0[r];
        sw[co * 65 + 32 + n] = acc1[r];
    }

    int co2 = lane >> 1;
    int ppb = (lane & 1) * 8;
    float bias = params[(size_t)i * P_TOTAL + 13216 + co2];
    unsigned short outv[8] __attribute__((aligned(16)));
#pragma unroll
    for (int it = 0; it < 8; ++it) {
        int pp = ppb + it;
        int py = pp >> 2, px = pp & 3;
        const float* s = sw + co2 * 65 + (py * 2) * 8 + px * 2;
        float v = fmaxf(fmaxf(s[0], s[1]), fmaxf(s[8], s[9]));
        outv[it] = f2bf(fmaxf(v + bias, 0.f));
    }
    int j = jbase + w;
    uint4* op = (uint4*)(act2 + ((size_t)i * 128 + j) * 512 + co2 * 16 + ppb);
    *op = *(const uint4*)outv;
}

// ---------------- Kernel 4: dense (10x512) + log_softmax ----------------
__global__ __launch_bounds__(256) void dense_kernel(const float* __restrict__ params,
                                                    const unsigned short* __restrict__ act2,
                                                    float* __restrict__ out) {
    int wid = blockIdx.x * 4 + (threadIdx.x >> 6);
    int lane = threadIdx.x & 63;
    int i = wid >> 7;

    const unsigned short* xp = act2 + (size_t)wid * 512 + lane * 8;
    uint4 u = *(const uint4*)xp;
    float xr[8];
    xr[0] = bf2f((unsigned short)(u.x & 0xffffu)); xr[1] = bf2f((unsigned short)(u.x >> 16));
    xr[2] = bf2f((unsigned short)(u.y & 0xffffu)); xr[3] = bf2f((unsigned short)(u.y >> 16));
    xr[4] = bf2f((unsigned short)(u.z & 0xffffu)); xr[5] = bf2f((unsigned short)(u.z >> 16));
    xr[6] = bf2f((unsigned short)(u.w & 0xffffu)); xr[7] = bf2f((unsigned short)(u.w >> 16));

    const float* wp = params + (size_t)i * P_TOTAL + 13248 + lane * 8;
    float acc[10];
#pragma unroll
    for (int o = 0; o < 10; ++o) {
        const float* wv = wp + o * 512;
        float a = 0.f;
#pragma unroll
        for (int k = 0; k < 8; ++k) a = fmaf(xr[k], wv[k], a);
#pragma unroll
        for (int d = 32; d >= 1; d >>= 1) a += __shfl_xor(a, d, 64);
        acc[o] = a;
    }
    const float* bp = params + (size_t)i * P_TOTAL + 18368;
    float m = -3.4e38f;
#pragma unroll
    for (int o = 0; o < 10; ++o) { acc[o] += bp[o]; m = fmaxf(m, acc[o]); }
    float ssum = 0.f;
#pragma unroll
    for (int o = 0; o < 10; ++o) ssum += expf(acc[o] - m);
    float ls = logf(ssum) + m;
    if (lane == 0) {
        float* op = out + (size_t)wid * 10;
#pragma unroll
        for (int o = 0; o < 10; ++o) op[o] = acc[o] - ls;
    }
}

extern "C" void kernel_launch(void* const* d_in, const int* in_sizes, int n_in,
                              void* d_out, int out_size, void* d_ws, size_t ws_size,
                              hipStream_t stream) {
    const float* params = (const float*)d_in[0];   // (64, 18378) fp32
    const float* batch  = (const float*)d_in[1];   // (128, 1, 28, 28) fp32
    float* out = (float*)d_out;                    // (64, 128, 10) fp32

    // workspace layout (all 16B aligned):
    //   act1: 64*128*144*16 bf16 = 18,874,368 elems = 37,748,736 B
    //   act2: 64*128*512  bf16   =  4,194,304 elems =  8,388,608 B
    //   wswz: 64*25*32*16 bf16   =    819,200 elems =  1,638,400 B
    //   Amat: 64*16*32    bf16   =     32,768 elems =     65,536 B
    //   Bmat: 128*576*32  bf16   =  2,359,296 elems =  4,718,592 B
    unsigned short* act1 = (unsigned short*)d_ws;
    unsigned short* act2 = act1 + (size_t)64 * 128 * 2304;
    unsigned short* wswz = act2 + (size_t)64 * 128 * 512;
    unsigned short* Amat = wswz + (size_t)64 * 12800;
    unsigned short* Bmat = Amat + (size_t)64 * 512;

    prep_kernel<<<128, 256, 0, stream>>>(params, wswz, Amat);
    im2col_kernel<<<128, 256, 0, stream>>>(batch, Bmat);
    conv1_gemm_kernel<<<512, 256, 0, stream>>>(params, Amat, Bmat, act1);
    conv2_mfma_kernel<<<2048, 256, 0, stream>>>(params, act1, wswz, act2);
    dense_kernel<<<2048, 256, 0, stream>>>(params, act2, out);
}

// Round 4
// 122.910 us; speedup vs baseline: 1.2607x; 1.2607x over previous
//
#include <hip/hip_runtime.h>
#include <hip/hip_bf16.h>
#include <math.h>

// Problem constants
#define P_TOTAL 18378
// param breakpoints (floats): w1 [0,400), b1 [400,416), w2 [416,13216),
// b2 [13216,13248), w3 [13248,18368), b3 [18368,18378)

typedef __attribute__((ext_vector_type(8))) short short8;
typedef __attribute__((ext_vector_type(4))) float float4v;
typedef __attribute__((ext_vector_type(16))) float float16;

__device__ __forceinline__ unsigned short f2bf(float f) {
    union { float f; unsigned u; } v; v.f = f;
    unsigned r = v.u + 0x7fffu + ((v.u >> 16) & 1u);
    return (unsigned short)(r >> 16);
}
__device__ __forceinline__ float bf2f(unsigned short h) {
    union { unsigned u; float f; } v; v.u = ((unsigned)h) << 16;
    return v.f;
}

// ---------------- Kernel 0: param prep + batch im2col (merged) ----------------
// blocks 0..63:    conv2 weights -> bf16 [init][tap][co=32][cin=16]
// blocks 64..127:  conv1 weights -> bf16 [init][co16][k=32pad]
// blocks 128..255: im2col of image (blk-128): Bmat[img][c][32k], c = pp*4+q,
//                  pp = py*12+px (pooled pixel), q = dy*2+dx.
__global__ __launch_bounds__(256) void prep_kernel(const float* __restrict__ params,
                                                   const float* __restrict__ batch,
                                                   unsigned short* __restrict__ wswz,
                                                   unsigned short* __restrict__ Amat,
                                                   unsigned short* __restrict__ Bmat) {
    int blk = blockIdx.x;
    if (blk < 64) {
        int i = blk;
        const float* w2 = params + (size_t)i * P_TOTAL + 416;   // [co32][cin16][5][5]
        unsigned short* dst = wswz + (size_t)i * 12800;
        for (int k = threadIdx.x; k < 12800; k += 256) {
            int co = k / 400;
            int r = k - co * 400;
            int cin = r / 25;
            int s = r - cin * 25;   // s = ky*5+kx
            dst[(s * 32 + co) * 16 + cin] = f2bf(w2[k]);
        }
    } else if (blk < 128) {
        int i = blk - 64;
        const float* w1 = params + (size_t)i * P_TOTAL;          // [co16][25]
        unsigned short* dst = Amat + (size_t)i * 512;
        for (int e = threadIdx.x; e < 512; e += 256) {
            int m = e >> 5, k = e & 31;
            dst[e] = (k < 25) ? f2bf(w1[m * 25 + k]) : (unsigned short)0;
        }
    } else {
        __shared__ float img[784];
        int j = blk - 128;
        int t = threadIdx.x;
        const float* ip = batch + j * 784;
        for (int k = t; k < 784; k += 256) img[k] = ip[k];
        __syncthreads();
        unsigned short* dst = Bmat + (size_t)j * 18432;
        for (int task = t; task < 2304; task += 256) {
            int c = task >> 2, kh = task & 3;
            int pp = c >> 2, q = c & 3;
            int py = pp / 12, px = pp - py * 12;
            int y0 = 2 * py + (q >> 1);
            int x0 = 2 * px + (q & 1);
            unsigned short ov[8] __attribute__((aligned(16)));
#pragma unroll
            for (int u = 0; u < 8; ++u) {
                int k = kh * 8 + u;
                float v = 0.f;
                if (k < 25) {
                    int ky = k / 5, kx = k - ky * 5;
                    v = img[(y0 + ky) * 28 + x0 + kx];
                }
                ov[u] = f2bf(v);
            }
            *(uint4*)(dst + c * 32 + kh * 8) = *(const uint4*)ov;
        }
    }
}

// ---------------- Kernel 1: conv1 as K=32 MFMA GEMM, pool in-register ----------------
// A = im2col pixels (M=576, row = pp*4+q), B = weights (N=16 co), one
// mfma_16x16x32 per (M-tile, init). D: col=lane&15=co, row=(lane>>4)*4+reg = c.
// The 4 regs of a lane = the 4 quad pixels of pooled pixel pp = nt*4+(lane>>4):
// pooling = 3 in-register fmax, zero cross-lane ops.
// Grid = 128 img x 4 init-groups = 512 blocks, 256 thr; wave w -> 4 inits.
#define B_ROW 40   // LDS row stride (elems): 80 B -> bank sweep covers all 32 banks
__global__ __launch_bounds__(256) void conv1_gemm_kernel(
        const float* __restrict__ params,
        const unsigned short* __restrict__ Amat,   // [64 init][16 co][32 k] (weights)
        const unsigned short* __restrict__ Bmat,   // [img][576 c][32 k] (im2col)
        unsigned short* __restrict__ act1) {       // [pair][144 pix][16 cin]
    __shared__ unsigned short blds[576 * B_ROW];   // 46080 B (im2col)
    __shared__ unsigned short alds[16 * 512];      // 16384 B (weights, 16 inits)
    int blk = blockIdx.x;
    int j  = blk >> 2;       // image
    int ig = blk & 3;        // init group (16 inits)
    int t = threadIdx.x;

    { // stage weights (16 KB straight copy)
        const uint4* src = (const uint4*)(Amat + (size_t)ig * 16 * 512);
        uint4* dst = (uint4*)alds;
        for (int k = t; k < 1024; k += 256) dst[k] = src[k];
    }
    { // stage im2col with padded rows
        const uint4* src = (const uint4*)(Bmat + (size_t)j * 18432);
        for (int k = t; k < 2304; k += 256) {
            int c = k >> 2, kh = k & 3;
            *(uint4*)(blds + c * B_ROW + kh * 8) = src[k];
        }
    }
    __syncthreads();

    int w = t >> 6, lane = t & 63;
    int co = lane & 15;       // B col (co) and A row low bits
    int h = lane >> 4;        // k-group for operand regs; pool-group row for D

    short8 wfr[4];
    float bias[4];
    unsigned short* obase[4];
#pragma unroll
    for (int mt = 0; mt < 4; ++mt) {
        int il = w * 4 + mt;
        int init = ig * 16 + il;
        wfr[mt] = *(const short8*)(alds + il * 512 + co * 32 + h * 8);
        bias[mt] = params[(size_t)init * P_TOTAL + 400 + co];
        obase[mt] = act1 + ((size_t)(init * 128 + j) * 144 + h) * 16 + co;
    }

#pragma unroll 4
    for (int nt = 0; nt < 36; ++nt) {
        short8 afr = *(const short8*)(blds + (nt * 16 + co) * B_ROW + h * 8);
#pragma unroll
        for (int mt = 0; mt < 4; ++mt) {
            float4v acc = {0.f, 0.f, 0.f, 0.f};
            acc = __builtin_amdgcn_mfma_f32_16x16x32_bf16(afr, wfr[mt], acc, 0, 0, 0);
            float v = fmaxf(fmaxf(acc[0], acc[1]), fmaxf(acc[2], acc[3]));
            v = fmaxf(v + bias[mt], 0.f);
            obase[mt][(size_t)nt * 64] = f2bf(v);   // pix = nt*4+h, elem stride 16
        }
    }
}

// ---------------- Kernel 2: conv2 via MFMA implicit GEMM ----------------
#define A1_PIX_STRIDE 24        // elems (48 B) in LDS
#define IMG_LDS (144 * 24)      // 3456 elems = 6912 B per image
__global__ __launch_bounds__(256) void conv2_mfma_kernel(
        const float* __restrict__ params,
        const unsigned short* __restrict__ act1,   // [pair][144][16] bf16
        const unsigned short* __restrict__ wswz,   // [init][25][32][16] bf16
        unsigned short* __restrict__ act2) {       // [pair][32co][16pp] bf16
    __shared__ char smem[58880];
    unsigned short* wlds = (unsigned short*)smem;            // 25600 B
    unsigned short* a1s  = (unsigned short*)(smem + 25600);  // 27648 B
    float* scratch       = (float*)(smem + 25600);           // 33280 B (reuses a1s)

    int b = blockIdx.x;
    int i = b >> 5;           // init
    int g = b & 31;           // image group
    int jbase = g * 4;
    int t = threadIdx.x;
    int w = t >> 6;           // wave = image index within group
    int lane = t & 63;

    {
        const uint4* src = (const uint4*)(wswz + (size_t)i * 12800);
        uint4* dst = (uint4*)wlds;
        for (int k = t; k < 1600; k += 256) dst[k] = src[k];
    }
    {
        for (int k = t; k < 1152; k += 256) {
            int img = k / 288;
            int rem = k - img * 288;
            int pix = rem >> 1;
            int h   = rem & 1;
            const uint4* src = (const uint4*)(act1 +
                ((size_t)(i * 128 + jbase + img) * 144 + pix) * 16 + h * 8);
            uint4* dst = (uint4*)(a1s + img * IMG_LDS + pix * A1_PIX_STRIDE + h * 8);
            *dst = *src;
        }
    }
    __syncthreads();

    int n = lane & 31;
    int h = lane >> 5;
    const short8* aptr = (const short8*)(wlds + n * 16 + h * 8);
    int y0 = n >> 3, x0 = n & 7;
    const unsigned short* bbase = a1s + w * IMG_LDS;
    const short8* bptr0 = (const short8*)(bbase + ((y0    ) * 12 + x0) * A1_PIX_STRIDE + h * 8);
    const short8* bptr1 = (const short8*)(bbase + ((y0 + 4) * 12 + x0) * A1_PIX_STRIDE + h * 8);

    float16 acc0 = {};
    float16 acc1 = {};
#pragma unroll
    for (int ky = 0; ky < 5; ++ky) {
#pragma unroll
        for (int kx = 0; kx < 5; ++kx) {
            int tap = ky * 5 + kx;
            short8 af = aptr[tap * 64];
            int bo = (ky * 12 + kx) * 3;
            short8 b0 = bptr0[bo];
            short8 b1 = bptr1[bo];
            acc0 = __builtin_amdgcn_mfma_f32_32x32x16_bf16(af, b0, acc0, 0, 0, 0);
            acc1 = __builtin_amdgcn_mfma_f32_32x32x16_bf16(af, b1, acc1, 0, 0, 0);
        }
    }
    __syncthreads();

    float* sw = scratch + w * 2080;
#pragma unroll
    for (int r = 0; r < 16; ++r) {
        int co = (r & 3) + 8 * (r >> 2) + 4 * h;
        sw[co * 65 + n]      = acc0[r];
        sw[co * 65 + 32 + n] = acc1[r];
    }

    int co2 = lane >> 1;
    int ppb = (lane & 1) * 8;
    float bias = params[(size_t)i * P_TOTAL + 13216 + co2];
    unsigned short outv[8] __attribute__((aligned(16)));
#pragma unroll
    for (int it = 0; it < 8; ++it) {
        int pp = ppb + it;
        int py = pp >> 2, px = pp & 3;
        const float* s = sw + co2 * 65 + (py * 2) * 8 + px * 2;
        float v = fmaxf(fmaxf(s[0], s[1]), fmaxf(s[8], s[9]));
        outv[it] = f2bf(fmaxf(v + bias, 0.f));
    }
    int j = jbase + w;
    uint4* op = (uint4*)(act2 + ((size_t)i * 128 + j) * 512 + co2 * 16 + ppb);
    *op = *(const uint4*)outv;
}

// ---------------- Kernel 3: dense (10x512) + log_softmax ----------------
__global__ __launch_bounds__(256) void dense_kernel(const float* __restrict__ params,
                                                    const unsigned short* __restrict__ act2,
                                                    float* __restrict__ out) {
    int wid = blockIdx.x * 4 + (threadIdx.x >> 6);
    int lane = threadIdx.x & 63;
    int i = wid >> 7;

    const unsigned short* xp = act2 + (size_t)wid * 512 + lane * 8;
    uint4 u = *(const uint4*)xp;
    float xr[8];
    xr[0] = bf2f((unsigned short)(u.x & 0xffffu)); xr[1] = bf2f((unsigned short)(u.x >> 16));
    xr[2] = bf2f((unsigned short)(u.y & 0xffffu)); xr[3] = bf2f((unsigned short)(u.y >> 16));
    xr[4] = bf2f((unsigned short)(u.z & 0xffffu)); xr[5] = bf2f((unsigned short)(u.z >> 16));
    xr[6] = bf2f((unsigned short)(u.w & 0xffffu)); xr[7] = bf2f((unsigned short)(u.w >> 16));

    const float* wp = params + (size_t)i * P_TOTAL + 13248 + lane * 8;
    float acc[10];
#pragma unroll
    for (int o = 0; o < 10; ++o) {
        const float* wv = wp + o * 512;
        float a = 0.f;
#pragma unroll
        for (int k = 0; k < 8; ++k) a = fmaf(xr[k], wv[k], a);
#pragma unroll
        for (int d = 32; d >= 1; d >>= 1) a += __shfl_xor(a, d, 64);
        acc[o] = a;
    }
    const float* bp = params + (size_t)i * P_TOTAL + 18368;
    float m = -3.4e38f;
#pragma unroll
    for (int o = 0; o < 10; ++o) { acc[o] += bp[o]; m = fmaxf(m, acc[o]); }
    float ssum = 0.f;
#pragma unroll
    for (int o = 0; o < 10; ++o) ssum += expf(acc[o] - m);
    float ls = logf(ssum) + m;
    if (lane == 0) {
        float* op = out + (size_t)wid * 10;
#pragma unroll
        for (int o = 0; o < 10; ++o) op[o] = acc[o] - ls;
    }
}

extern "C" void kernel_launch(void* const* d_in, const int* in_sizes, int n_in,
                              void* d_out, int out_size, void* d_ws, size_t ws_size,
                              hipStream_t stream) {
    const float* params = (const float*)d_in[0];   // (64, 18378) fp32
    const float* batch  = (const float*)d_in[1];   // (128, 1, 28, 28) fp32
    float* out = (float*)d_out;                    // (64, 128, 10) fp32

    // workspace layout (all 16B aligned):
    //   act1: 64*128*144*16 bf16 = 18,874,368 elems = 37,748,736 B
    //   act2: 64*128*512  bf16   =  4,194,304 elems =  8,388,608 B
    //   wswz: 64*25*32*16 bf16   =    819,200 elems =  1,638,400 B
    //   Amat: 64*16*32    bf16   =     32,768 elems =     65,536 B
    //   Bmat: 128*576*32  bf16   =  2,359,296 elems =  4,718,592 B
    unsigned short* act1 = (unsigned short*)d_ws;
    unsigned short* act2 = act1 + (size_t)64 * 128 * 2304;
    unsigned short* wswz = act2 + (size_t)64 * 128 * 512;
    unsigned short* Amat = wswz + (size_t)64 * 12800;
    unsigned short* Bmat = Amat + (size_t)64 * 512;

    prep_kernel<<<256, 256, 0, stream>>>(params, batch, wswz, Amat, Bmat);
    conv1_gemm_kernel<<<512, 256, 0, stream>>>(params, Amat, Bmat, act1);
    conv2_mfma_kernel<<<2048, 256, 0, stream>>>(params, act1, wswz, act2);
    dense_kernel<<<2048, 256, 0, stream>>>(params, act2, out);
}